// Round 8
// baseline (554.466 us; speedup 1.0000x reference)
//
#include <hip/hip_runtime.h>
#include <math.h>

#define TT 256
#define HIDDEN 2048
#define NH 16
#define HD 128
#define KDIM 2048
#define NCG 30

typedef _Float16 h2 __attribute__((ext_vector_type(2)));
typedef _Float16 h4 __attribute__((ext_vector_type(4)));
typedef _Float16 half8 __attribute__((ext_vector_type(8)));
typedef float floatx4 __attribute__((ext_vector_type(4)));

__device__ __forceinline__ float wave_sum64(float v) {
#pragma unroll
    for (int off = 32; off > 0; off >>= 1) v += __shfl_xor(v, off, 64);
    return v;
}

__device__ __forceinline__ half8 cvt8(const float4 x, const float4 y) {
    half8 f;
    f[0] = (_Float16)x.x; f[1] = (_Float16)x.y; f[2] = (_Float16)x.z; f[3] = (_Float16)x.w;
    f[4] = (_Float16)y.x; f[5] = (_Float16)y.y; f[6] = (_Float16)y.z; f[7] = (_Float16)y.w;
    return f;
}

// ============ one-time weight transpose+cvt: Wt[n][k] f16 from W[k][n] f32 ============
__global__ __launch_bounds__(256) void wtrans_kernel(
    const float* __restrict__ W0, const float* __restrict__ W1,
    const float* __restrict__ W2, const float* __restrict__ W3,
    _Float16* __restrict__ T0, _Float16* __restrict__ T1,
    _Float16* __restrict__ T2, _Float16* __restrict__ T3)
{
    __shared__ float tile[64][68];
    const int z = blockIdx.z;
    const float* __restrict__ W = (z == 0) ? W0 : (z == 1) ? W1 : (z == 2) ? W2 : W3;
    _Float16* __restrict__ T = (z == 0) ? T0 : (z == 1) ? T1 : (z == 2) ? T2 : T3;
    const int k0 = blockIdx.x * 64, n0 = blockIdx.y * 64;
    const int tid = threadIdx.x;
#pragma unroll
    for (int p = 0; p < 4; p++) {
        const int idx = p * 256 + tid;
        const int r = idx >> 4, c = (idx & 15) * 4;
        const float4 v = *(const float4*)&W[(k0 + r) * KDIM + n0 + c];
        tile[r][c] = v.x; tile[r][c + 1] = v.y; tile[r][c + 2] = v.z; tile[r][c + 3] = v.w;
    }
    __syncthreads();
    const int n = tid & 63, kc = (tid >> 6) * 16;
    half8 o0, o1;
#pragma unroll
    for (int j = 0; j < 8; j++) o0[j] = (_Float16)tile[kc + j][n];
#pragma unroll
    for (int j = 0; j < 8; j++) o1[j] = (_Float16)tile[kc + 8 + j][n];
    *(half8*)&T[(size_t)(n0 + n) * KDIM + k0 + kc] = o0;
    *(half8*)&T[(size_t)(n0 + n) * KDIM + k0 + kc + 8] = o1;
}

// Tab[32][2048] f32: rows 0-15 = Wa^T, 16-31 = Wb^T
__global__ __launch_bounds__(256) void wab_trans_kernel(
    const float* __restrict__ Wa, const float* __restrict__ Wb, float* __restrict__ Tab)
{
    const int b = blockIdx.x;
    const int h = threadIdx.x & 15, kl = threadIdx.x >> 4;
    for (int p = 0; p < 16; p++) {
        const int k = b * 256 + p * 16 + kl;
        Tab[h * KDIM + k] = Wa[k * NH + h];
        Tab[(16 + h) * KDIM + k] = Wb[k * NH + h];
    }
}

// ============ barrier-free f16-MFMA GEMM: 32x128 tile, no LDS, DEPTH-4 pipeline ====
// Pipeline buffers are arrays indexed ONLY by fully-unrolled loop constants —
// SROA promotes them to VGPRs (runtime indices would force scratch: round-6 bug).
// ~24 outstanding loads/wave -> compiler emits partial vmcnt waits (AITER-style).
__global__ __launch_bounds__(256) void gemm_nb_kernel(
    const float* __restrict__ A,
    const _Float16* __restrict__ Bt0, const _Float16* __restrict__ Bt1,
    const _Float16* __restrict__ Bt2,
    float* __restrict__ C0, float* __restrict__ C1, float* __restrict__ C2,
    int nTilesPerMat)
{
    const int lane = threadIdx.x & 63, w = threadIdx.x >> 6;
    const int q = lane >> 4, l16 = lane & 15;
    const int nt = blockIdx.x, mt = blockIdx.y;
    const int mat = nt / nTilesPerMat;
    const int n0 = (nt - mat * nTilesPerMat) * 128;
    const _Float16* __restrict__ Bt = (mat == 0) ? Bt0 : (mat == 1) ? Bt1 : Bt2;
    float* __restrict__ C = (mat == 0) ? C0 : (mat == 1) ? C1 : C2;
    const int m0 = mt * 32;

    const float* __restrict__ Ar0 = &A[(size_t)(m0 + l16) * KDIM + q * 8];
    const float* __restrict__ Ar1 = Ar0 + (size_t)16 * KDIM;
    const _Float16* __restrict__ Br0 = &Bt[(size_t)(n0 + w * 32 + l16) * KDIM + q * 8];
    const _Float16* __restrict__ Br1 = Br0 + (size_t)16 * KDIM;

    floatx4 acc[2][2] = {};
    float4 pa[4][2][2];   // [stage][msub][half] — constant-indexed only
    half8 pb[4][2];       // [stage][nsub]

#pragma unroll
    for (int s = 0; s < 4; s++) {
        const int k = s * 32;
        pa[s][0][0] = *(const float4*)&Ar0[k]; pa[s][0][1] = *(const float4*)&Ar0[k + 4];
        pa[s][1][0] = *(const float4*)&Ar1[k]; pa[s][1][1] = *(const float4*)&Ar1[k + 4];
        pb[s][0] = *(const half8*)&Br0[k];
        pb[s][1] = *(const half8*)&Br1[k];
    }

    for (int k0 = 0; k0 < KDIM; k0 += 128) {
#pragma unroll
        for (int s = 0; s < 4; s++) {
            const half8 af0 = cvt8(pa[s][0][0], pa[s][0][1]);
            const half8 af1 = cvt8(pa[s][1][0], pa[s][1][1]);
            const half8 bf0 = pb[s][0], bf1 = pb[s][1];
            const int knx = k0 + 128 + s * 32;
            const int kp = (knx < KDIM) ? knx : (s * 32);   // clamp: harmless redundant load
            pa[s][0][0] = *(const float4*)&Ar0[kp]; pa[s][0][1] = *(const float4*)&Ar0[kp + 4];
            pa[s][1][0] = *(const float4*)&Ar1[kp]; pa[s][1][1] = *(const float4*)&Ar1[kp + 4];
            pb[s][0] = *(const half8*)&Br0[kp];
            pb[s][1] = *(const half8*)&Br1[kp];
            acc[0][0] = __builtin_amdgcn_mfma_f32_16x16x32_f16(af0, bf0, acc[0][0], 0, 0, 0);
            acc[0][1] = __builtin_amdgcn_mfma_f32_16x16x32_f16(af0, bf1, acc[0][1], 0, 0, 0);
            acc[1][0] = __builtin_amdgcn_mfma_f32_16x16x32_f16(af1, bf0, acc[1][0], 0, 0, 0);
            acc[1][1] = __builtin_amdgcn_mfma_f32_16x16x32_f16(af1, bf1, acc[1][1], 0, 0, 0);
        }
    }

#pragma unroll
    for (int r = 0; r < 4; r++) {
        C[(size_t)(m0 + q * 4 + r) * KDIM + n0 + w * 32 + l16] = acc[0][0][r];
        C[(size_t)(m0 + q * 4 + r) * KDIM + n0 + w * 32 + 16 + l16] = acc[0][1][r];
        C[(size_t)(m0 + 16 + q * 4 + r) * KDIM + n0 + w * 32 + l16] = acc[1][0][r];
        C[(size_t)(m0 + 16 + q * 4 + r) * KDIM + n0 + w * 32 + 16 + l16] = acc[1][1][r];
    }
}

// ---------------- g/beta projections (coalesced via Tab) ----------------
__global__ __launch_bounds__(256) void ab_kernel(
    const float* __restrict__ X, const float* __restrict__ Tab,
    const float* __restrict__ ba, const float* __restrict__ bb,
    float* __restrict__ g, float* __restrict__ beta)
{
    const int t = blockIdx.x;
    const int lane = threadIdx.x & 63, w = threadIdx.x >> 6;
    for (int oi = 0; oi < 8; oi++) {
        const int o = w * 8 + oi;
        const int h = o & 15, which = o >> 4;
        float acc = 0.f;
#pragma unroll
        for (int i = 0; i < 8; i++) {
            const int kk = lane * 4 + i * 256;
            const float4 xv = *(const float4*)&X[t * HIDDEN + kk];
            const float4 wv = *(const float4*)&Tab[o * KDIM + kk];
            acc = fmaf(xv.x, wv.x, acc); acc = fmaf(xv.y, wv.y, acc);
            acc = fmaf(xv.z, wv.z, acc); acc = fmaf(xv.w, wv.w, acc);
        }
        acc = wave_sum64(acc);
        if (lane == 0) {
            if (which == 0) {
                const float z = acc + ba[h];
                g[t * NH + h] = fminf(z, 0.f) - log1pf(__expf(-fabsf(z)));
            } else {
                const float z = acc + bb[h];
                beta[t * NH + h] = 1.f / (1.f + __expf(-z));
            }
        }
    }
}

// ---------------- prep: cumsum(g) + lamb = softplus + 0.25 ----------------
__global__ __launch_bounds__(256) void prep_kernel(const float* __restrict__ g,
                                                   float* __restrict__ G,
                                                   const float* __restrict__ lp,
                                                   float* __restrict__ lamb)
{
    __shared__ float gs[TT * NH];
    const int tid = threadIdx.x;
    for (int i = tid; i < KDIM; i += 256) {
        const float x = lp[i];
        lamb[i] = fmaxf(x, 0.f) + log1pf(__expf(-fabsf(x))) + 0.25f;
    }
    for (int i = tid; i < TT * NH; i += 256) gs[i] = g[i];
    __syncthreads();
    if (tid < NH) {
        float run = 0.f;
        for (int t = 0; t < TT; t++) { run += gs[t * NH + tid]; gs[t * NH + tid] = run; }
    }
    __syncthreads();
    for (int i = tid; i < TT * NH; i += 256) G[i] = gs[i];
}

// ---------------- conv(4)+silu+l2norm, q&k fused per (t,h) ----------------
__global__ __launch_bounds__(256) void conv_silu_l2_kernel(
    const float* __restrict__ q_pre, const float* __restrict__ k_pre,
    const float* __restrict__ cwq, const float* __restrict__ cwk,
    float* __restrict__ qn, float* __restrict__ kn)
{
    const int t = blockIdx.x, h = blockIdx.y;
    const int which = threadIdx.x >> 7, d = threadIdx.x & 127;
    const int w = threadIdx.x >> 6;
    const int c = h * HD + d;
    const float* pre = which ? k_pre : q_pre;
    const float* cw  = which ? cwk : cwq;
    float y = 0.f;
#pragma unroll
    for (int i = 0; i < 4; i++) {
        const int ts = t - 3 + i;
        if (ts >= 0) y = fmaf(pre[ts * KDIM + c], cw[c * 4 + i], y);
    }
    const float s = y / (1.f + __expf(-y));
    float v = s * s;
#pragma unroll
    for (int off = 32; off > 0; off >>= 1) v += __shfl_down(v, off, 64);
    __shared__ float red[4];
    if ((threadIdx.x & 63) == 0) red[w] = v;
    __syncthreads();
    const float sum = red[which * 2] + red[which * 2 + 1];
    float* dst = which ? kn : qn;
    dst[t * KDIM + c] = s * rsqrtf(sum + 1e-6f);
}

// ================= MFMA-batched mesa CG (spill-free) + fused rmsnorm =================
#define KTSTR 264
#define PSTR 136
#define YSTR 264
#define MESA_LDS (128 * KTSTR * 2 + 16 * PSTR * 2 + 16 * YSTR * 2 + 64 * 4)

template<int SMAX>
__device__ __forceinline__ void mesa_cg(
    const float* __restrict__ qn, const float* __restrict__ kn, const float* __restrict__ vv,
    const float* __restrict__ G, const float* __restrict__ bet, const float* __restrict__ lamb,
    const float* __restrict__ onw, float* __restrict__ out,
    int h, int t0, _Float16* Kt, _Float16* Psh, _Float16* Ysh, float* red)
{
    constexpr int NSUB1 = SMAX / 64;
    constexpr int NK2   = SMAX / 32;

    const int tid = threadIdx.x, lane = tid & 63, w = tid >> 6;
    const int quad = lane >> 4, l16 = lane & 15;
    const int tmy = t0 + l16;
    const int dbase = w * 32;

    {
        const int sd = tid & 127, sg = tid >> 7;
        for (int s0 = 0; s0 < SMAX; s0 += 8) {
            const int sb = s0 + sg * 4;
            h4 kv;
#pragma unroll
            for (int j = 0; j < 4; j++) kv[j] = (_Float16)kn[((sb + j) * NH + h) * HD + sd];
            *(h4*)&Kt[sd * KTSTR + sb] = kv;
        }
    }

    half8 K1[NSUB1][4];
#pragma unroll
    for (int ii = 0; ii < NSUB1; ii++) {
        const int srow = 16 * (w + 4 * ii) + l16;
        const float* kp = &kn[(srow * NH + h) * HD];
#pragma unroll
        for (int kk = 0; kk < 4; kk++) {
            const float4 a = *(const float4*)&kp[kk * 32 + quad * 8];
            const float4 b = *(const float4*)&kp[kk * 32 + quad * 8 + 4];
            K1[ii][kk] = cvt8(a, b);
        }
    }
    const float Gt = G[tmy * NH + h];
    float Wm[NSUB1][4];
#pragma unroll
    for (int ii = 0; ii < NSUB1; ii++)
#pragma unroll
        for (int r = 0; r < 4; r++) {
            const int s = 16 * (w + 4 * ii) + quad * 4 + r;
            Wm[ii][r] = (s <= tmy) ? bet[s * NH + h] * __expf(Gt - G[s * NH + h]) : 0.f;
        }
    float lam[8], xv[8], rv[8], pv[8];
#pragma unroll
    for (int ss = 0; ss < 2; ss++)
#pragma unroll
        for (int r = 0; r < 4; r++) {
            const int e = ss * 4 + r;
            const int d = dbase + ss * 16 + quad * 4 + r;
            lam[e] = lamb[h * HD + d];
            const float b = qn[(tmy * NH + h) * HD + d];
            xv[e] = 0.f; rv[e] = b; pv[e] = b;
        }
    float rs = 0.f;
#pragma unroll
    for (int e = 0; e < 8; e++) rs += rv[e] * rv[e];
    rs += __shfl_xor(rs, 16, 64); rs += __shfl_xor(rs, 32, 64);

    auto writeP = [&](const float* src) {
#pragma unroll
        for (int ss = 0; ss < 2; ss++) {
            h4 ph;
            ph.x = (_Float16)src[ss * 4 + 0]; ph.y = (_Float16)src[ss * 4 + 1];
            ph.z = (_Float16)src[ss * 4 + 2]; ph.w = (_Float16)src[ss * 4 + 3];
            *(h4*)&Psh[l16 * PSTR + dbase + ss * 16 + quad * 4] = ph;
        }
    };
    writeP(pv);

    for (int it = 0; it <= NCG; it++) {
        __syncthreads();
        floatx4 acc1[NSUB1] = {};
#pragma unroll
        for (int kk = 0; kk < 4; kk++) {
            const half8 bf = *(const half8*)&Psh[l16 * PSTR + kk * 32 + quad * 8];
#pragma unroll
            for (int ii = 0; ii < NSUB1; ii++)
                acc1[ii] = __builtin_amdgcn_mfma_f32_16x16x32_f16(K1[ii][kk], bf, acc1[ii], 0, 0, 0);
        }
#pragma unroll
        for (int ii = 0; ii < NSUB1; ii++) {
            h4 yh;
            yh.x = (_Float16)(Wm[ii][0] * acc1[ii][0]);
            yh.y = (_Float16)(Wm[ii][1] * acc1[ii][1]);
            yh.z = (_Float16)(Wm[ii][2] * acc1[ii][2]);
            yh.w = (_Float16)(Wm[ii][3] * acc1[ii][3]);
            *(h4*)&Ysh[l16 * YSTR + 16 * (w + 4 * ii) + quad * 4] = yh;
        }
        __syncthreads();
        if (it == NCG) break;

        floatx4 acc2[2] = {};
#pragma unroll
        for (int kk = 0; kk < NK2; kk++) {
            const half8 bf = *(const half8*)&Ysh[l16 * YSTR + kk * 32 + quad * 8];
#pragma unroll
            for (int ss = 0; ss < 2; ss++) {
                const half8 af = *(const half8*)&Kt[(dbase + ss * 16 + l16) * KTSTR + kk * 32 + quad * 8];
                acc2[ss] = __builtin_amdgcn_mfma_f32_16x16x32_f16(af, bf, acc2[ss], 0, 0, 0);
            }
        }
        float Ap[8], pAp = 0.f;
#pragma unroll
        for (int ss = 0; ss < 2; ss++)
#pragma unroll
            for (int r = 0; r < 4; r++) {
                const int e = ss * 4 + r;
                Ap[e] = acc2[ss][r] + lam[e] * pv[e];
                pAp += pv[e] * Ap[e];
            }
        pAp += __shfl_xor(pAp, 16, 64); pAp += __shfl_xor(pAp, 32, 64);
        const float alpha = rs / (pAp + 1e-12f);
        float rsn = 0.f;
#pragma unroll
        for (int e = 0; e < 8; e++) {
            xv[e] = fmaf(alpha, pv[e], xv[e]);
            rv[e] = fmaf(-alpha, Ap[e], rv[e]);
            rsn += rv[e] * rv[e];
        }
        rsn += __shfl_xor(rsn, 16, 64); rsn += __shfl_xor(rsn, 32, 64);
        const float bcg = rsn / (rs + 1e-12f);
#pragma unroll
        for (int e = 0; e < 8; e++) pv[e] = fmaf(bcg, pv[e], rv[e]);
        rs = rsn;
        writeP(it == NCG - 1 ? xv : pv);
    }

    floatx4 accO[2] = {};
#pragma unroll
    for (int kk = 0; kk < NK2; kk++) {
        const half8 af = *(const half8*)&Ysh[l16 * YSTR + kk * 32 + quad * 8];
#pragma unroll
        for (int ss = 0; ss < 2; ss++) {
            half8 bf;
#pragma unroll
            for (int jj = 0; jj < 8; jj++) {
                const int s = kk * 32 + quad * 8 + jj;
                bf[jj] = (_Float16)vv[(s * NH + h) * HD + dbase + ss * 16 + l16];
            }
            accO[ss] = __builtin_amdgcn_mfma_f32_16x16x32_f16(af, bf, accO[ss], 0, 0, 0);
        }
    }

    float part[4];
#pragma unroll
    for (int r = 0; r < 4; r++) {
        part[r] = accO[0][r] * accO[0][r] + accO[1][r] * accO[1][r];
#pragma unroll
        for (int off = 1; off < 16; off <<= 1) part[r] += __shfl_xor(part[r], off, 64);
    }
    if (l16 == 0) {
#pragma unroll
        for (int r = 0; r < 4; r++) red[w * 16 + quad * 4 + r] = part[r];
    }
    __syncthreads();
    const float w0 = onw[dbase + l16], w1 = onw[dbase + 16 + l16];
#pragma unroll
    for (int r = 0; r < 4; r++) {
        const int qr = quad * 4 + r;
        const float sumd = red[qr] + red[16 + qr] + red[32 + qr] + red[48 + qr];
        const float sc = rsqrtf(sumd * (1.f / HD) + 1e-5f);
        const int trow = ((t0 + qr) * NH + h) * HD;
        out[trow + dbase + l16] = accO[0][r] * sc * w0;
        out[trow + dbase + 16 + l16] = accO[1][r] * sc * w1;
    }
}

__global__ __launch_bounds__(256) void mesa_kernel(
    const float* __restrict__ qn, const float* __restrict__ kn, const float* __restrict__ vv,
    const float* __restrict__ G, const float* __restrict__ bet, const float* __restrict__ lamb,
    const float* __restrict__ onw, float* __restrict__ out)
{
    extern __shared__ char smem_raw[];
    _Float16* Kt  = (_Float16*)smem_raw;
    _Float16* Psh = (_Float16*)(smem_raw + 128 * KTSTR * 2);
    _Float16* Ysh = (_Float16*)(smem_raw + 128 * KTSTR * 2 + 16 * PSTR * 2);
    float* red = (float*)(smem_raw + 128 * KTSTR * 2 + 16 * PSTR * 2 + 16 * YSTR * 2);
    const int h = blockIdx.x, jb = blockIdx.y, t0 = jb * 16;
    switch (jb >> 2) {
        case 0:  mesa_cg<64> (qn, kn, vv, G, bet, lamb, onw, out, h, t0, Kt, Psh, Ysh, red); break;
        case 1:  mesa_cg<128>(qn, kn, vv, G, bet, lamb, onw, out, h, t0, Kt, Psh, Ysh, red); break;
        case 2:  mesa_cg<192>(qn, kn, vv, G, bet, lamb, onw, out, h, t0, Kt, Psh, Ysh, red); break;
        default: mesa_cg<256>(qn, kn, vv, G, bet, lamb, onw, out, h, t0, Kt, Psh, Ysh, red); break;
    }
}

extern "C" void kernel_launch(void* const* d_in, const int* in_sizes, int n_in,
                              void* d_out, int out_size, void* d_ws, size_t ws_size,
                              hipStream_t stream)
{
    (void)in_sizes; (void)n_in; (void)out_size; (void)ws_size;
    const float* x   = (const float*)d_in[0];
    const float* Wq  = (const float*)d_in[1];
    const float* Wk  = (const float*)d_in[2];
    const float* Wv  = (const float*)d_in[3];
    const float* Wa  = (const float*)d_in[4];
    const float* ba  = (const float*)d_in[5];
    const float* Wb  = (const float*)d_in[6];
    const float* bb  = (const float*)d_in[7];
    const float* cwq = (const float*)d_in[8];
    const float* cwk = (const float*)d_in[9];
    const float* lp  = (const float*)d_in[10];
    const float* onw = (const float*)d_in[11];
    const float* Wo  = (const float*)d_in[12];

    char* wsb = (char*)d_ws;
    float* q_pre = (float*)wsb;
    float* k_pre = q_pre + 524288;
    float* v     = k_pre + 524288;
    float* qn    = v + 524288;
    float* kn    = qn + 524288;
    float* g     = kn + 524288;
    float* beta  = g + 4096;
    float* G     = beta + 4096;
    float* lamb  = G + 4096;
    size_t off = ((size_t)((char*)(lamb + 2048) - wsb) + 1023) & ~(size_t)1023;
    _Float16* WtQ = (_Float16*)(wsb + off);
    _Float16* WtK = WtQ + (size_t)KDIM * KDIM;
    _Float16* WtV = WtK + (size_t)KDIM * KDIM;
    _Float16* WtO = WtV + (size_t)KDIM * KDIM;
    float* Tab    = (float*)(WtO + (size_t)KDIM * KDIM);
    float* onorm  = q_pre;
    float* outp   = (float*)d_out;

    wtrans_kernel<<<dim3(32, 32, 4), 256, 0, stream>>>(Wq, Wk, Wv, Wo, WtQ, WtK, WtV, WtO);
    wab_trans_kernel<<<8, 256, 0, stream>>>(Wa, Wb, Tab);

    gemm_nb_kernel<<<dim3(48, 8), 256, 0, stream>>>(x, WtQ, WtK, WtV, q_pre, k_pre, v, 16);
    ab_kernel<<<dim3(TT), 256, 0, stream>>>(x, Tab, ba, bb, g, beta);
    prep_kernel<<<1, 256, 0, stream>>>(g, G, lp, lamb);
    conv_silu_l2_kernel<<<dim3(TT, NH), 256, 0, stream>>>(q_pre, k_pre, cwq, cwk, qn, kn);

    (void)hipFuncSetAttribute((const void*)mesa_kernel,
                              hipFuncAttributeMaxDynamicSharedMemorySize, MESA_LDS);
    mesa_kernel<<<dim3(NH, 16), 256, MESA_LDS, stream>>>(qn, kn, v, G, beta, lamb, onw, onorm);

    gemm_nb_kernel<<<dim3(16, 8), 256, 0, stream>>>(onorm, WtO, WtO, WtO, outp, outp, outp, 16);
}

// Round 9
// 256.101 us; speedup vs baseline: 2.1650x; 2.1650x over previous
//
#include <hip/hip_runtime.h>
#include <math.h>

#define TT 256
#define HIDDEN 2048
#define NH 16
#define HD 128
#define KDIM 2048
#define NCG 30

typedef _Float16 h2 __attribute__((ext_vector_type(2)));
typedef _Float16 h4 __attribute__((ext_vector_type(4)));
typedef _Float16 half8 __attribute__((ext_vector_type(8)));
typedef float floatx4 __attribute__((ext_vector_type(4)));

__device__ __forceinline__ float wave_sum64(float v) {
#pragma unroll
    for (int off = 32; off > 0; off >>= 1) v += __shfl_xor(v, off, 64);
    return v;
}

__device__ __forceinline__ half8 cvt8(const float4 x, const float4 y) {
    half8 f;
    f[0] = (_Float16)x.x; f[1] = (_Float16)x.y; f[2] = (_Float16)x.z; f[3] = (_Float16)x.w;
    f[4] = (_Float16)y.x; f[5] = (_Float16)y.y; f[6] = (_Float16)y.z; f[7] = (_Float16)y.w;
    return f;
}

// async 16B/lane global->LDS (dest = wave-uniform base + lane*16)
__device__ __forceinline__ void glds16(const void* g, void* l) {
    __builtin_amdgcn_global_load_lds(
        (const __attribute__((address_space(1))) void*)g,
        (__attribute__((address_space(3))) void*)l, 16, 0, 0);
}

// ============ one-time weight cvt into GEMM-blocked f16 layout ============
// B_blk half-offset = ((nt*64 + kt)*4 + kc)*1024 + nn*8 + j
//   where n = nt*128+nn, k = kt*32 + kc*8 + j.
// Each (nt,kt) 32k x 128n tile is a contiguous 8 KB block -> coalesced DMA.
__global__ __launch_bounds__(256) void wtrans_kernel(
    const float* __restrict__ W0, const float* __restrict__ W1,
    const float* __restrict__ W2, const float* __restrict__ W3,
    _Float16* __restrict__ T0, _Float16* __restrict__ T1,
    _Float16* __restrict__ T2, _Float16* __restrict__ T3)
{
    __shared__ float tile[64][68];
    const int z = blockIdx.z;
    const float* __restrict__ W = (z == 0) ? W0 : (z == 1) ? W1 : (z == 2) ? W2 : W3;
    _Float16* __restrict__ T = (z == 0) ? T0 : (z == 1) ? T1 : (z == 2) ? T2 : T3;
    const int k0 = blockIdx.x * 64, n0 = blockIdx.y * 64;
    const int tid = threadIdx.x;
#pragma unroll
    for (int p = 0; p < 4; p++) {
        const int idx = p * 256 + tid;
        const int r = idx >> 4, c = (idx & 15) * 4;
        const float4 v = *(const float4*)&W[(size_t)(k0 + r) * KDIM + n0 + c];
        tile[r][c] = v.x; tile[r][c + 1] = v.y; tile[r][c + 2] = v.z; tile[r][c + 3] = v.w;
    }
    __syncthreads();
#pragma unroll
    for (int p = 0; p < 2; p++) {
        const int c = p * 256 + tid;          // chunk: dn = c>>3, c8 = c&7
        const int dn = c >> 3, c8 = c & 7;
        const int gk = k0 + c8 * 8, gn = n0 + dn;
        const int nt = gn >> 7, nn = gn & 127;
        const int kt = gk >> 5, kc = (gk >> 3) & 3;
        half8 o;
#pragma unroll
        for (int j = 0; j < 8; j++) o[j] = (_Float16)tile[c8 * 8 + j][dn];
        *(half8*)&T[(size_t)(((nt * 64 + kt) * 4 + kc)) * 1024 + nn * 8] = o;
    }
}

// Tab[32][2048] f32: rows 0-15 = Wa^T, 16-31 = Wb^T
__global__ __launch_bounds__(256) void wab_trans_kernel(
    const float* __restrict__ Wa, const float* __restrict__ Wb, float* __restrict__ Tab)
{
    const int b = blockIdx.x;
    const int h = threadIdx.x & 15, kl = threadIdx.x >> 4;
    for (int p = 0; p < 16; p++) {
        const int k = b * 256 + p * 16 + kl;
        Tab[h * KDIM + k] = Wa[k * NH + h];
        Tab[(16 + h) * KDIM + k] = Wb[k * NH + h];
    }
}

// ============ m97-style f16-MFMA GEMM: 32x128 tile, BK=64, dbuf LDS ============
// B staged via global_load_lds (width 16, coalesced, blocked layout);
// A staged f32->f16 via registers. 2-way LDS bank aliasing everywhere (free).
#define ASTR 72   // halves per A row (64 + 8 pad)
__global__ __launch_bounds__(256) void gemm_kernel(
    const float* __restrict__ A,
    const _Float16* __restrict__ Bb0, const _Float16* __restrict__ Bb1,
    const _Float16* __restrict__ Bb2,
    float* __restrict__ C0, float* __restrict__ C1, float* __restrict__ C2,
    int nTilesPerMat)
{
    __shared__ __align__(16) _Float16 Bsh[2][8192];   // 16 KB each: [kt2][kc][n][8]
    __shared__ __align__(16) _Float16 Ash[2][32 * ASTR];

    const int tid = threadIdx.x, lane = tid & 63, w = tid >> 6;
    const int q = lane >> 4, l16 = lane & 15;
    const int nt = blockIdx.x, mt = blockIdx.y;
    const int mat = nt / nTilesPerMat;
    const int ntile = nt - mat * nTilesPerMat;
    const int n0 = ntile * 128;
    const _Float16* __restrict__ Bb = (mat == 0) ? Bb0 : (mat == 1) ? Bb1 : Bb2;
    float* __restrict__ C = (mat == 0) ? C0 : (mat == 1) ? C1 : C2;
    const int m0 = mt * 32;

    const _Float16* __restrict__ Btile = Bb + (size_t)ntile * 262144;  // 128n x 2048k
    const int ar = tid >> 3, ac = (tid & 7) * 8;
    const float* __restrict__ Ap = &A[(size_t)(m0 + ar) * KDIM + ac];

    floatx4 acc[2][2] = {};
    float4 ax, ay;

    // prologue: DMA B(0), stage A(0), preload A(1) regs
#pragma unroll
    for (int i = 0; i < 4; i++)
        glds16(Btile + (size_t)((w * 4 + i) * 64 + lane) * 8, &Bsh[0][(w * 4 + i) * 512]);
    ax = *(const float4*)&Ap[0]; ay = *(const float4*)&Ap[4];
    *(half8*)&Ash[0][ar * ASTR + ac] = cvt8(ax, ay);
    ax = *(const float4*)&Ap[64]; ay = *(const float4*)&Ap[68];
    __syncthreads();   // drains B-DMA(0); Ash[0] visible

    const int NSTEP = KDIM / 64;   // 32
    for (int s = 0; s < NSTEP; s++) {
        const int cur = s & 1;
        if (s + 1 < NSTEP) {       // DMA B(s+1) into other buffer, in flight during compute
            const _Float16* src = Btile + (size_t)(s + 1) * 8192;
#pragma unroll
            for (int i = 0; i < 4; i++)
                glds16(src + (size_t)((w * 4 + i) * 64 + lane) * 8, &Bsh[cur ^ 1][(w * 4 + i) * 512]);
        }
#pragma unroll
        for (int kk = 0; kk < 2; kk++) {
            const half8 bf0 = *(const half8*)&Bsh[cur][kk * 4096 + q * 1024 + (w * 32 + l16) * 8];
            const half8 bf1 = *(const half8*)&Bsh[cur][kk * 4096 + q * 1024 + (w * 32 + 16 + l16) * 8];
            const half8 af0 = *(const half8*)&Ash[cur][l16 * ASTR + kk * 32 + q * 8];
            const half8 af1 = *(const half8*)&Ash[cur][(16 + l16) * ASTR + kk * 32 + q * 8];
            acc[0][0] = __builtin_amdgcn_mfma_f32_16x16x32_f16(af0, bf0, acc[0][0], 0, 0, 0);
            acc[0][1] = __builtin_amdgcn_mfma_f32_16x16x32_f16(af0, bf1, acc[0][1], 0, 0, 0);
            acc[1][0] = __builtin_amdgcn_mfma_f32_16x16x32_f16(af1, bf0, acc[1][0], 0, 0, 0);
            acc[1][1] = __builtin_amdgcn_mfma_f32_16x16x32_f16(af1, bf1, acc[1][1], 0, 0, 0);
        }
        if (s + 1 < NSTEP) {
            *(half8*)&Ash[cur ^ 1][ar * ASTR + ac] = cvt8(ax, ay);   // stage A(s+1)
            if (s + 2 < NSTEP) {
                ax = *(const float4*)&Ap[(s + 2) * 64];
                ay = *(const float4*)&Ap[(s + 2) * 64 + 4];
            }
        }
        __syncthreads();   // drains B-DMA(s+1), Ash(s+1) visible, guards buffer reuse
    }

#pragma unroll
    for (int r = 0; r < 4; r++) {
        C[(size_t)(m0 + q * 4 + r) * KDIM + n0 + w * 32 + l16] = acc[0][0][r];
        C[(size_t)(m0 + q * 4 + r) * KDIM + n0 + w * 32 + 16 + l16] = acc[0][1][r];
        C[(size_t)(m0 + 16 + q * 4 + r) * KDIM + n0 + w * 32 + l16] = acc[1][0][r];
        C[(size_t)(m0 + 16 + q * 4 + r) * KDIM + n0 + w * 32 + 16 + l16] = acc[1][1][r];
    }
}

// ---------------- g/beta projections (coalesced via Tab) ----------------
__global__ __launch_bounds__(256) void ab_kernel(
    const float* __restrict__ X, const float* __restrict__ Tab,
    const float* __restrict__ ba, const float* __restrict__ bb,
    float* __restrict__ g, float* __restrict__ beta)
{
    const int t = blockIdx.x;
    const int lane = threadIdx.x & 63, w = threadIdx.x >> 6;
    for (int oi = 0; oi < 8; oi++) {
        const int o = w * 8 + oi;
        const int h = o & 15, which = o >> 4;
        float acc = 0.f;
#pragma unroll
        for (int i = 0; i < 8; i++) {
            const int kk = lane * 4 + i * 256;
            const float4 xv = *(const float4*)&X[t * HIDDEN + kk];
            const float4 wv = *(const float4*)&Tab[o * KDIM + kk];
            acc = fmaf(xv.x, wv.x, acc); acc = fmaf(xv.y, wv.y, acc);
            acc = fmaf(xv.z, wv.z, acc); acc = fmaf(xv.w, wv.w, acc);
        }
        acc = wave_sum64(acc);
        if (lane == 0) {
            if (which == 0) {
                const float z = acc + ba[h];
                g[t * NH + h] = fminf(z, 0.f) - log1pf(__expf(-fabsf(z)));
            } else {
                const float z = acc + bb[h];
                beta[t * NH + h] = 1.f / (1.f + __expf(-z));
            }
        }
    }
}

// ---------------- prep: cumsum(g) + lamb = softplus + 0.25 ----------------
__global__ __launch_bounds__(256) void prep_kernel(const float* __restrict__ g,
                                                   float* __restrict__ G,
                                                   const float* __restrict__ lp,
                                                   float* __restrict__ lamb)
{
    __shared__ float gs[TT * NH];
    const int tid = threadIdx.x;
    for (int i = tid; i < KDIM; i += 256) {
        const float x = lp[i];
        lamb[i] = fmaxf(x, 0.f) + log1pf(__expf(-fabsf(x))) + 0.25f;
    }
    for (int i = tid; i < TT * NH; i += 256) gs[i] = g[i];
    __syncthreads();
    if (tid < NH) {
        float run = 0.f;
        for (int t = 0; t < TT; t++) { run += gs[t * NH + tid]; gs[t * NH + tid] = run; }
    }
    __syncthreads();
    for (int i = tid; i < TT * NH; i += 256) G[i] = gs[i];
}

// ---------------- conv(4)+silu+l2norm, q&k fused per (t,h) ----------------
__global__ __launch_bounds__(256) void conv_silu_l2_kernel(
    const float* __restrict__ q_pre, const float* __restrict__ k_pre,
    const float* __restrict__ cwq, const float* __restrict__ cwk,
    float* __restrict__ qn, float* __restrict__ kn)
{
    const int t = blockIdx.x, h = blockIdx.y;
    const int which = threadIdx.x >> 7, d = threadIdx.x & 127;
    const int w = threadIdx.x >> 6;
    const int c = h * HD + d;
    const float* pre = which ? k_pre : q_pre;
    const float* cw  = which ? cwk : cwq;
    float y = 0.f;
#pragma unroll
    for (int i = 0; i < 4; i++) {
        const int ts = t - 3 + i;
        if (ts >= 0) y = fmaf(pre[ts * KDIM + c], cw[c * 4 + i], y);
    }
    const float s = y / (1.f + __expf(-y));
    float v = s * s;
#pragma unroll
    for (int off = 32; off > 0; off >>= 1) v += __shfl_down(v, off, 64);
    __shared__ float red[4];
    if ((threadIdx.x & 63) == 0) red[w] = v;
    __syncthreads();
    const float sum = red[which * 2] + red[which * 2 + 1];
    float* dst = which ? kn : qn;
    dst[t * KDIM + c] = s * rsqrtf(sum + 1e-6f);
}

// ================= MFMA-batched mesa CG (spill-free) + fused rmsnorm =================
#define KTSTR 264
#define PSTR 136
#define YSTR 264
#define MESA_LDS (128 * KTSTR * 2 + 16 * PSTR * 2 + 16 * YSTR * 2 + 64 * 4)

template<int SMAX>
__device__ __forceinline__ void mesa_cg(
    const float* __restrict__ qn, const float* __restrict__ kn, const float* __restrict__ vv,
    const float* __restrict__ G, const float* __restrict__ bet, const float* __restrict__ lamb,
    const float* __restrict__ onw, float* __restrict__ out,
    int h, int t0, _Float16* Kt, _Float16* Psh, _Float16* Ysh, float* red)
{
    constexpr int NSUB1 = SMAX / 64;
    constexpr int NK2   = SMAX / 32;

    const int tid = threadIdx.x, lane = tid & 63, w = tid >> 6;
    const int quad = lane >> 4, l16 = lane & 15;
    const int tmy = t0 + l16;
    const int dbase = w * 32;

    {
        const int sd = tid & 127, sg = tid >> 7;
        for (int s0 = 0; s0 < SMAX; s0 += 8) {
            const int sb = s0 + sg * 4;
            h4 kv;
#pragma unroll
            for (int j = 0; j < 4; j++) kv[j] = (_Float16)kn[((sb + j) * NH + h) * HD + sd];
            *(h4*)&Kt[sd * KTSTR + sb] = kv;
        }
    }

    half8 K1[NSUB1][4];
#pragma unroll
    for (int ii = 0; ii < NSUB1; ii++) {
        const int srow = 16 * (w + 4 * ii) + l16;
        const float* kp = &kn[(srow * NH + h) * HD];
#pragma unroll
        for (int kk = 0; kk < 4; kk++) {
            const float4 a = *(const float4*)&kp[kk * 32 + quad * 8];
            const float4 b = *(const float4*)&kp[kk * 32 + quad * 8 + 4];
            K1[ii][kk] = cvt8(a, b);
        }
    }
    const float Gt = G[tmy * NH + h];
    float Wm[NSUB1][4];
#pragma unroll
    for (int ii = 0; ii < NSUB1; ii++)
#pragma unroll
        for (int r = 0; r < 4; r++) {
            const int s = 16 * (w + 4 * ii) + quad * 4 + r;
            Wm[ii][r] = (s <= tmy) ? bet[s * NH + h] * __expf(Gt - G[s * NH + h]) : 0.f;
        }
    float lam[8], xv[8], rv[8], pv[8];
#pragma unroll
    for (int ss = 0; ss < 2; ss++)
#pragma unroll
        for (int r = 0; r < 4; r++) {
            const int e = ss * 4 + r;
            const int d = dbase + ss * 16 + quad * 4 + r;
            lam[e] = lamb[h * HD + d];
            const float b = qn[(tmy * NH + h) * HD + d];
            xv[e] = 0.f; rv[e] = b; pv[e] = b;
        }
    float rs = 0.f;
#pragma unroll
    for (int e = 0; e < 8; e++) rs += rv[e] * rv[e];
    rs += __shfl_xor(rs, 16, 64); rs += __shfl_xor(rs, 32, 64);

    auto writeP = [&](const float* src) {
#pragma unroll
        for (int ss = 0; ss < 2; ss++) {
            h4 ph;
            ph.x = (_Float16)src[ss * 4 + 0]; ph.y = (_Float16)src[ss * 4 + 1];
            ph.z = (_Float16)src[ss * 4 + 2]; ph.w = (_Float16)src[ss * 4 + 3];
            *(h4*)&Psh[l16 * PSTR + dbase + ss * 16 + quad * 4] = ph;
        }
    };
    writeP(pv);

    for (int it = 0; it <= NCG; it++) {
        __syncthreads();
        floatx4 acc1[NSUB1] = {};
#pragma unroll
        for (int kk = 0; kk < 4; kk++) {
            const half8 bf = *(const half8*)&Psh[l16 * PSTR + kk * 32 + quad * 8];
#pragma unroll
            for (int ii = 0; ii < NSUB1; ii++)
                acc1[ii] = __builtin_amdgcn_mfma_f32_16x16x32_f16(K1[ii][kk], bf, acc1[ii], 0, 0, 0);
        }
#pragma unroll
        for (int ii = 0; ii < NSUB1; ii++) {
            h4 yh;
            yh.x = (_Float16)(Wm[ii][0] * acc1[ii][0]);
            yh.y = (_Float16)(Wm[ii][1] * acc1[ii][1]);
            yh.z = (_Float16)(Wm[ii][2] * acc1[ii][2]);
            yh.w = (_Float16)(Wm[ii][3] * acc1[ii][3]);
            *(h4*)&Ysh[l16 * YSTR + 16 * (w + 4 * ii) + quad * 4] = yh;
        }
        __syncthreads();
        if (it == NCG) break;

        floatx4 acc2[2] = {};
#pragma unroll
        for (int kk = 0; kk < NK2; kk++) {
            const half8 bf = *(const half8*)&Ysh[l16 * YSTR + kk * 32 + quad * 8];
#pragma unroll
            for (int ss = 0; ss < 2; ss++) {
                const half8 af = *(const half8*)&Kt[(dbase + ss * 16 + l16) * KTSTR + kk * 32 + quad * 8];
                acc2[ss] = __builtin_amdgcn_mfma_f32_16x16x32_f16(af, bf, acc2[ss], 0, 0, 0);
            }
        }
        float Ap[8], pAp = 0.f;
#pragma unroll
        for (int ss = 0; ss < 2; ss++)
#pragma unroll
            for (int r = 0; r < 4; r++) {
                const int e = ss * 4 + r;
                Ap[e] = acc2[ss][r] + lam[e] * pv[e];
                pAp += pv[e] * Ap[e];
            }
        pAp += __shfl_xor(pAp, 16, 64); pAp += __shfl_xor(pAp, 32, 64);
        const float alpha = rs / (pAp + 1e-12f);
        float rsn = 0.f;
#pragma unroll
        for (int e = 0; e < 8; e++) {
            xv[e] = fmaf(alpha, pv[e], xv[e]);
            rv[e] = fmaf(-alpha, Ap[e], rv[e]);
            rsn += rv[e] * rv[e];
        }
        rsn += __shfl_xor(rsn, 16, 64); rsn += __shfl_xor(rsn, 32, 64);
        const float bcg = rsn / (rs + 1e-12f);
#pragma unroll
        for (int e = 0; e < 8; e++) pv[e] = fmaf(bcg, pv[e], rv[e]);
        rs = rsn;
        writeP(it == NCG - 1 ? xv : pv);
    }

    floatx4 accO[2] = {};
#pragma unroll
    for (int kk = 0; kk < NK2; kk++) {
        const half8 af = *(const half8*)&Ysh[l16 * YSTR + kk * 32 + quad * 8];
#pragma unroll
        for (int ss = 0; ss < 2; ss++) {
            half8 bf;
#pragma unroll
            for (int jj = 0; jj < 8; jj++) {
                const int s = kk * 32 + quad * 8 + jj;
                bf[jj] = (_Float16)vv[(s * NH + h) * HD + dbase + ss * 16 + l16];
            }
            accO[ss] = __builtin_amdgcn_mfma_f32_16x16x32_f16(af, bf, accO[ss], 0, 0, 0);
        }
    }

    float part[4];
#pragma unroll
    for (int r = 0; r < 4; r++) {
        part[r] = accO[0][r] * accO[0][r] + accO[1][r] * accO[1][r];
#pragma unroll
        for (int off = 1; off < 16; off <<= 1) part[r] += __shfl_xor(part[r], off, 64);
    }
    if (l16 == 0) {
#pragma unroll
        for (int r = 0; r < 4; r++) red[w * 16 + quad * 4 + r] = part[r];
    }
    __syncthreads();
    const float w0 = onw[dbase + l16], w1 = onw[dbase + 16 + l16];
#pragma unroll
    for (int r = 0; r < 4; r++) {
        const int qr = quad * 4 + r;
        const float sumd = red[qr] + red[16 + qr] + red[32 + qr] + red[48 + qr];
        const float sc = rsqrtf(sumd * (1.f / HD) + 1e-5f);
        const int trow = ((t0 + qr) * NH + h) * HD;
        out[trow + dbase + l16] = accO[0][r] * sc * w0;
        out[trow + dbase + 16 + l16] = accO[1][r] * sc * w1;
    }
}

__global__ __launch_bounds__(256) void mesa_kernel(
    const float* __restrict__ qn, const float* __restrict__ kn, const float* __restrict__ vv,
    const float* __restrict__ G, const float* __restrict__ bet, const float* __restrict__ lamb,
    const float* __restrict__ onw, float* __restrict__ out)
{
    extern __shared__ char smem_raw[];
    _Float16* Kt  = (_Float16*)smem_raw;
    _Float16* Psh = (_Float16*)(smem_raw + 128 * KTSTR * 2);
    _Float16* Ysh = (_Float16*)(smem_raw + 128 * KTSTR * 2 + 16 * PSTR * 2);
    float* red = (float*)(smem_raw + 128 * KTSTR * 2 + 16 * PSTR * 2 + 16 * YSTR * 2);
    const int h = blockIdx.x, jb = blockIdx.y, t0 = jb * 16;
    switch (jb >> 2) {
        case 0:  mesa_cg<64> (qn, kn, vv, G, bet, lamb, onw, out, h, t0, Kt, Psh, Ysh, red); break;
        case 1:  mesa_cg<128>(qn, kn, vv, G, bet, lamb, onw, out, h, t0, Kt, Psh, Ysh, red); break;
        case 2:  mesa_cg<192>(qn, kn, vv, G, bet, lamb, onw, out, h, t0, Kt, Psh, Ysh, red); break;
        default: mesa_cg<256>(qn, kn, vv, G, bet, lamb, onw, out, h, t0, Kt, Psh, Ysh, red); break;
    }
}

extern "C" void kernel_launch(void* const* d_in, const int* in_sizes, int n_in,
                              void* d_out, int out_size, void* d_ws, size_t ws_size,
                              hipStream_t stream)
{
    (void)in_sizes; (void)n_in; (void)out_size; (void)ws_size;
    const float* x   = (const float*)d_in[0];
    const float* Wq  = (const float*)d_in[1];
    const float* Wk  = (const float*)d_in[2];
    const float* Wv  = (const float*)d_in[3];
    const float* Wa  = (const float*)d_in[4];
    const float* ba  = (const float*)d_in[5];
    const float* Wb  = (const float*)d_in[6];
    const float* bb  = (const float*)d_in[7];
    const float* cwq = (const float*)d_in[8];
    const float* cwk = (const float*)d_in[9];
    const float* lp  = (const float*)d_in[10];
    const float* onw = (const float*)d_in[11];
    const float* Wo  = (const float*)d_in[12];

    char* wsb = (char*)d_ws;
    float* q_pre = (float*)wsb;
    float* k_pre = q_pre + 524288;
    float* v     = k_pre + 524288;
    float* qn    = v + 524288;
    float* kn    = qn + 524288;
    float* g     = kn + 524288;
    float* beta  = g + 4096;
    float* G     = beta + 4096;
    float* lamb  = G + 4096;
    size_t off = ((size_t)((char*)(lamb + 2048) - wsb) + 1023) & ~(size_t)1023;
    _Float16* WtQ = (_Float16*)(wsb + off);
    _Float16* WtK = WtQ + (size_t)KDIM * KDIM;
    _Float16* WtV = WtK + (size_t)KDIM * KDIM;
    _Float16* WtO = WtV + (size_t)KDIM * KDIM;
    float* Tab    = (float*)(WtO + (size_t)KDIM * KDIM);
    float* onorm  = q_pre;
    float* outp   = (float*)d_out;

    wtrans_kernel<<<dim3(32, 32, 4), 256, 0, stream>>>(Wq, Wk, Wv, Wo, WtQ, WtK, WtV, WtO);
    wab_trans_kernel<<<8, 256, 0, stream>>>(Wa, Wb, Tab);

    gemm_kernel<<<dim3(48, 8), 256, 0, stream>>>(x, WtQ, WtK, WtV, q_pre, k_pre, v, 16);
    ab_kernel<<<dim3(TT), 256, 0, stream>>>(x, Tab, ba, bb, g, beta);
    prep_kernel<<<1, 256, 0, stream>>>(g, G, lp, lamb);
    conv_silu_l2_kernel<<<dim3(TT, NH), 256, 0, stream>>>(q_pre, k_pre, cwq, cwk, qn, kn);

    (void)hipFuncSetAttribute((const void*)mesa_kernel,
                              hipFuncAttributeMaxDynamicSharedMemorySize, MESA_LDS);
    mesa_kernel<<<dim3(NH, 16), 256, MESA_LDS, stream>>>(qn, kn, v, G, beta, lamb, onw, onorm);

    gemm_kernel<<<dim3(16, 8), 256, 0, stream>>>(onorm, WtO, WtO, WtO, outp, outp, outp, 16);
}